// Round 8
// baseline (60.057 us; speedup 1.0000x reference)
//
#include <hip/hip_runtime.h>
#include <hip/hip_bf16.h>

#define DD   512
#define NH   32
#define AA   18
#define JJ   (NH*AA)          // 576
#define BB   4096
#define JD   (JJ*DD)          // 294912

typedef short bf16x8 __attribute__((ext_vector_type(8)));
typedef float f32x4  __attribute__((ext_vector_type(4)));

static __device__ inline unsigned short f2bf(float f) {
    unsigned int x = __float_as_uint(f);
    unsigned int r = (x + 0x7fffu + ((x >> 16) & 1u)) >> 16;   // RNE
    return (unsigned short)r;
}
static __device__ inline float bf2f(unsigned short bits) {
    return __uint_as_float((unsigned int)bits << 16);
}

// ---------------------------------------------------------------------------
// K1: block (es 0..7, n 0..31) = 256 blocks x 256 thr.
//  a) convert private 32KB slice of x -> bf16
//  b) stage U[18][512] f32 in LDS; es==0 blocks fold c1[j]=sum_e U*b2
//  c) partial V over e-slab [es*64, es*64+64): reads W2 rows WHOLE
//     (2KB contiguous per row), f32 FMA, U via b128 LDS broadcast.
//     2-way rg merge in dead-U LDS; write Vp[es] as bf16.
// ---------------------------------------------------------------------------
__global__ __launch_bounds__(256) void k_V(
    const float* __restrict__ x, unsigned short* __restrict__ Xb,
    const float* __restrict__ W2, const float* __restrict__ Wv,
    const float* __restrict__ Wa, const float* __restrict__ b2,
    unsigned short* __restrict__ Vp, float* __restrict__ c1)
{
    const int t  = threadIdx.x;
    const int es = blockIdx.x;          // 0..7
    const int n  = blockIdx.y;          // 0..31

    __shared__ __align__(16) float smem[AA * DD];     // 36864 B: us, later red
    __shared__ float redc[AA * 4];
    float*  us   = smem;
    float4* red4 = (float4*)smem;                     // 2304 float4 (exact fit)

    // --- a) convX slice
    {
        const int bid = n*8 + es;
        const float4* xin = (const float4*)x + (size_t)bid*2048;
        ushort4*      xo  = (ushort4*)Xb + (size_t)bid*2048;
        #pragma unroll
        for (int i = 0; i < 8; ++i) {
            const float4 v = xin[t + 256*i];
            ushort4 o;
            o.x = f2bf(v.x); o.y = f2bf(v.y); o.z = f2bf(v.z); o.w = f2bf(v.w);
            xo[t + 256*i] = o;
        }
    }

    // --- b) stage U (R5-validated)
    for (int el = t; el < DD; el += 256) {
        float wa[AA]; float msum = 0.f;
        #pragma unroll
        for (int a = 0; a < AA; ++a) {
            wa[a] = Wa[(size_t)(n*AA + a)*DD + el];
            msum += wa[a];
        }
        msum *= (1.0f / 18.0f);
        const float wv = Wv[(size_t)n*DD + el];
        #pragma unroll
        for (int a = 0; a < AA; ++a) us[a*DD + el] = wv + wa[a] - msum;
    }
    __syncthreads();

    // c1 on es==0 blocks (R5-validated; block-uniform branch)
    if (es == 0) {
        float p[AA];
        const float b2a = b2[(size_t)n*DD + t];
        const float b2b = b2[(size_t)n*DD + t + 256];
        #pragma unroll
        for (int a = 0; a < AA; ++a)
            p[a] = us[a*DD + t]*b2a + us[a*DD + t + 256]*b2b;
        #pragma unroll
        for (int a = 0; a < AA; ++a)
            for (int o = 32; o; o >>= 1) p[a] += __shfl_xor(p[a], o, 64);
        if ((t & 63) == 0) {
            const int w = t >> 6;
            #pragma unroll
            for (int a = 0; a < AA; ++a) redc[a*4 + w] = p[a];
        }
        __syncthreads();
        if (t < AA)
            c1[n*AA + t] = redc[t*4] + redc[t*4+1] + redc[t*4+2] + redc[t*4+3];
    }

    // --- c) main: full-row streaming over e-slab
    const int col4 = t & 127;            // float4 column index (0..127)
    const int rg   = t >> 7;             // 0..1, each owns 32 rows
    const int e0   = es*64 + rg*32;
    const float* wrow = W2 + ((size_t)n*DD + e0)*DD + col4*4;

    float4 acc[AA];
    #pragma unroll
    for (int a = 0; a < AA; ++a) acc[a] = make_float4(0.f,0.f,0.f,0.f);

    #pragma unroll 2
    for (int i4 = 0; i4 < 8; ++i4) {
        float4 w4[4];
        #pragma unroll
        for (int j = 0; j < 4; ++j)
            w4[j] = *(const float4*)(wrow + (size_t)(i4*4 + j)*DD);
        const int eo = e0 + i4*4;
        #pragma unroll
        for (int a = 0; a < AA; ++a) {
            const float4 u4 = *(const float4*)(us + a*DD + eo);
            acc[a].x += u4.x*w4[0].x + u4.y*w4[1].x + u4.z*w4[2].x + u4.w*w4[3].x;
            acc[a].y += u4.x*w4[0].y + u4.y*w4[1].y + u4.z*w4[2].y + u4.w*w4[3].y;
            acc[a].z += u4.x*w4[0].z + u4.y*w4[1].z + u4.z*w4[2].z + u4.w*w4[3].z;
            acc[a].w += u4.x*w4[0].w + u4.y*w4[1].w + u4.z*w4[2].w + u4.w*w4[3].w;
        }
    }
    __syncthreads();                     // all waves done reading us

    if (rg == 0) {
        #pragma unroll
        for (int a = 0; a < AA; ++a) red4[a*128 + col4] = acc[a];
    }
    __syncthreads();
    if (rg == 1) {
        #pragma unroll
        for (int a = 0; a < AA; ++a) {
            float4 r = red4[a*128 + col4];
            r.x += acc[a].x; r.y += acc[a].y; r.z += acc[a].z; r.w += acc[a].w;
            red4[a*128 + col4] = r;
        }
    }
    __syncthreads();

    // write Vp[es] bf16 (layout [es][j][d])
    unsigned short* vout = Vp + (size_t)es*JD + (size_t)n*AA*DD;
    for (int q = t; q < AA*128; q += 256) {
        const float4 v = red4[q];
        ushort4 o;
        o.x = f2bf(v.x); o.y = f2bf(v.y); o.z = f2bf(v.z); o.w = f2bf(v.w);
        *(ushort4*)(vout + q*4) = o;
    }
}

// ---------------------------------------------------------------------------
// K2: block (kp 0..3, n 0..31) = 128 blocks x 256 thr.
//  a) stage Vsum[18][512] f32 = sum of 8 bf16 Vp slabs
//  b) kp==0: c3[j] = c1 + Vsum.b1 + bv + ba - mean(ba)
//  c) M[a, kp-panel] = sum_d Vsum[a,d]*W1[d,k]: reads W1 rows in 512B
//     contiguous chunks, all 512 d per block -> direct bf16 M output.
//     8 rg groups merged via shfl_xor(32) -> 4 wave-partials in dead-vs LDS.
// ---------------------------------------------------------------------------
__global__ __launch_bounds__(256) void k_M(
    const float* __restrict__ W1, const unsigned short* __restrict__ Vp,
    const float* __restrict__ b1, const float* __restrict__ bv,
    const float* __restrict__ ba, const float* __restrict__ c1,
    unsigned short* __restrict__ Mb, float* __restrict__ c3)
{
    const int t  = threadIdx.x;
    const int kp = blockIdx.x;          // 0..3
    const int n  = blockIdx.y;          // 0..31

    __shared__ __align__(16) float smem[AA * DD];     // 36864 B: vs, later red
    __shared__ float redc[AA * 4];
    float*  vs   = smem;
    float4* red4 = (float4*)smem;

    // --- a) vs = sum of 8 Vp slabs
    for (int q = t; q < AA*128; q += 256) {           // f4 index
        float4 s = make_float4(0.f,0.f,0.f,0.f);
        #pragma unroll
        for (int es = 0; es < 8; ++es) {
            const ushort4 u = *(const ushort4*)(Vp + (size_t)es*JD + (size_t)n*AA*DD + q*4);
            s.x += bf2f(u.x); s.y += bf2f(u.y); s.z += bf2f(u.z); s.w += bf2f(u.w);
        }
        ((float4*)vs)[q] = s;
    }
    __syncthreads();

    // --- b) c3 on kp==0 (R5-validated pattern)
    if (kp == 0) {
        float p[AA];
        const float b1a = b1[(size_t)n*DD + t];
        const float b1b = b1[(size_t)n*DD + t + 256];
        #pragma unroll
        for (int a = 0; a < AA; ++a)
            p[a] = vs[a*DD + t]*b1a + vs[a*DD + t + 256]*b1b;
        #pragma unroll
        for (int a = 0; a < AA; ++a)
            for (int o = 32; o; o >>= 1) p[a] += __shfl_xor(p[a], o, 64);
        if ((t & 63) == 0) {
            const int w = t >> 6;
            #pragma unroll
            for (int a = 0; a < AA; ++a) redc[a*4 + w] = p[a];
        }
        __syncthreads();
        if (t < AA) {
            float bam = 0.f;
            #pragma unroll
            for (int a = 0; a < AA; ++a) bam += ba[n*AA + a];
            c3[n*AA + t] = c1[n*AA + t]
                         + redc[t*4] + redc[t*4+1] + redc[t*4+2] + redc[t*4+3]
                         + bv[n] + ba[n*AA + t] - bam * (1.0f/18.0f);
        }
    }

    // --- c) main: all 512 d, 128-col k-panel
    const int col4 = t & 31;             // f4 col in panel (0..31)
    const int rg   = t >> 5;             // 0..7, each owns 64 d-rows
    const int w    = t >> 6;
    const int lane = t & 63;
    const float* wrow = W1 + ((size_t)n*DD + rg*64)*DD + kp*128 + col4*4;

    float4 acc[AA];
    #pragma unroll
    for (int a = 0; a < AA; ++a) acc[a] = make_float4(0.f,0.f,0.f,0.f);

    #pragma unroll 2
    for (int i4 = 0; i4 < 16; ++i4) {
        float4 w4[4];
        #pragma unroll
        for (int j = 0; j < 4; ++j)
            w4[j] = *(const float4*)(wrow + (size_t)(i4*4 + j)*DD);
        const int d0 = rg*64 + i4*4;
        #pragma unroll
        for (int a = 0; a < AA; ++a) {
            const float4 u4 = *(const float4*)(vs + a*DD + d0);
            acc[a].x += u4.x*w4[0].x + u4.y*w4[1].x + u4.z*w4[2].x + u4.w*w4[3].x;
            acc[a].y += u4.x*w4[0].y + u4.y*w4[1].y + u4.z*w4[2].y + u4.w*w4[3].y;
            acc[a].z += u4.x*w4[0].z + u4.y*w4[1].z + u4.z*w4[2].z + u4.w*w4[3].z;
            acc[a].w += u4.x*w4[0].w + u4.y*w4[1].w + u4.z*w4[2].w + u4.w*w4[3].w;
        }
    }
    __syncthreads();                     // all waves done reading vs

    // merge rg pairs within wave, then 4 wave-partials via LDS
    #pragma unroll
    for (int a = 0; a < AA; ++a) {
        acc[a].x += __shfl_xor(acc[a].x, 32, 64);
        acc[a].y += __shfl_xor(acc[a].y, 32, 64);
        acc[a].z += __shfl_xor(acc[a].z, 32, 64);
        acc[a].w += __shfl_xor(acc[a].w, 32, 64);
    }
    if (lane < 32) {
        #pragma unroll
        for (int a = 0; a < AA; ++a)
            red4[(w*AA + a)*32 + col4] = acc[a];     // 4 x 576 f4 = exact fit
    }
    __syncthreads();

    // final sum over 4 wave-partials + bf16 write
    for (int q = t; q < AA*32; q += 256) {           // 576 outputs (f4)
        const float4 r0 = red4[q],        r1 = red4[576 + q];
        const float4 r2 = red4[1152 + q], r3 = red4[1728 + q];
        float4 s;
        s.x = r0.x + r1.x + r2.x + r3.x;
        s.y = r0.y + r1.y + r2.y + r3.y;
        s.z = r0.z + r1.z + r2.z + r3.z;
        s.w = r0.w + r1.w + r2.w + r3.w;
        const int a = q >> 5, c4 = q & 31;
        ushort4 o;
        o.x = f2bf(s.x); o.y = f2bf(s.y); o.z = f2bf(s.z); o.w = f2bf(s.w);
        *(ushort4*)(Mb + (size_t)(n*AA + a)*DD + kp*128 + c4*4) = o;
    }
}

// ---------------------------------------------------------------------------
// K3: out[b,j] = sum_k Xb[b,k]*Mb[j,k] + c3[j]   (bf16 MFMA)
//     R5/R6-validated: BM=64 BN=64 BK=64, 4 waves, XOR-swizzled LDS.
// ---------------------------------------------------------------------------
#define GBM 64
#define GBN 64
#define GBK 64

__global__ __launch_bounds__(256) void k_gemm(
    const unsigned short* __restrict__ Xb,   // [4096][512] bf16 bits
    const unsigned short* __restrict__ Mb,   // [576][512]  bf16 bits
    const float* __restrict__ c3, float* __restrict__ out)
{
    __shared__ __align__(16) unsigned short xs[GBM * GBK];   // 8 KB
    __shared__ __align__(16) unsigned short ms[GBN * GBK];   // 8 KB

    const int t    = threadIdx.x;
    const int w    = t >> 6;
    const int lane = t & 63;
    const int ln   = lane & 15, lg = lane >> 4;
    const int wm   = w >> 1,   wn = w & 1;
    const int b0 = blockIdx.x * GBM;
    const int j0 = blockIdx.y * GBN;

    f32x4 acc[2][2] = {};

    for (int kc = 0; kc < DD; kc += GBK) {
        #pragma unroll
        for (int it = 0; it < 2; ++it) {
            const int chunk = it*256 + t;
            const int row = chunk >> 3, slot = chunk & 7;
            const int4 vx = *(const int4*)(Xb + (size_t)(b0 + row)*DD + kc + slot*8);
            *(int4*)(xs + row*GBK + ((slot ^ (row & 7)) * 8)) = vx;
            const int4 vm = *(const int4*)(Mb + (size_t)(j0 + row)*DD + kc + slot*8);
            *(int4*)(ms + row*GBK + ((slot ^ (row & 7)) * 8)) = vm;
        }
        __syncthreads();

        #pragma unroll
        for (int kk = 0; kk < 2; ++kk) {
            bf16x8 av[2], bv[2];
            #pragma unroll
            for (int mt = 0; mt < 2; ++mt) {
                const int row  = 32*wm + 16*mt + ln;
                const int slot = (4*kk + lg) ^ (row & 7);
                av[mt] = *(const bf16x8*)(xs + row*GBK + slot*8);
            }
            #pragma unroll
            for (int nt = 0; nt < 2; ++nt) {
                const int row  = 32*wn + 16*nt + ln;
                const int slot = (4*kk + lg) ^ (row & 7);
                bv[nt] = *(const bf16x8*)(ms + row*GBK + slot*8);
            }
            #pragma unroll
            for (int mt = 0; mt < 2; ++mt)
                #pragma unroll
                for (int nt = 0; nt < 2; ++nt)
                    acc[mt][nt] = __builtin_amdgcn_mfma_f32_16x16x32_bf16(
                        av[mt], bv[nt], acc[mt][nt], 0, 0, 0);
        }
        __syncthreads();
    }

    // C/D layout: col=lane&15, row=(lane>>4)*4+reg  [m89/m91]
    float c3v[2];
    #pragma unroll
    for (int nt = 0; nt < 2; ++nt) c3v[nt] = c3[j0 + 32*wn + 16*nt + ln];

    #pragma unroll
    for (int mt = 0; mt < 2; ++mt)
        #pragma unroll
        for (int nt = 0; nt < 2; ++nt) {
            const int j = j0 + 32*wn + 16*nt + ln;
            #pragma unroll
            for (int r = 0; r < 4; ++r) {
                const int b = b0 + 32*wm + 16*mt + 4*lg + r;
                out[(size_t)b*JJ + j] = acc[mt][nt][r] + c3v[nt];
            }
        }
}

// ---------------------------------------------------------------------------
extern "C" void kernel_launch(void* const* d_in, const int* in_sizes, int n_in,
                              void* d_out, int out_size, void* d_ws, size_t ws_size,
                              hipStream_t stream)
{
    const float* x  = (const float*)d_in[0];
    const float* W1 = (const float*)d_in[1];
    const float* b1 = (const float*)d_in[2];
    const float* W2 = (const float*)d_in[3];
    const float* b2 = (const float*)d_in[4];
    const float* Wv = (const float*)d_in[5];
    const float* bv = (const float*)d_in[6];
    const float* Wa = (const float*)d_in[7];
    const float* ba = (const float*)d_in[8];
    float* out = (float*)d_out;
    float* ws  = (float*)d_ws;

    // ws: c1[JJ] f32 | c3[JJ] f32 | Xb[BB*DD] u16 | Vp[8*JD] u16 | Mb[JD] u16
    float* c1 = ws;
    float* c3 = c1 + JJ;
    unsigned short* Xb = (unsigned short*)(c3 + JJ);
    unsigned short* Vp = Xb + (size_t)BB*DD;
    unsigned short* Mb = Vp + (size_t)8*JD;

    k_V   <<<dim3(8, NH), 256, 0, stream>>>(x, Xb, W2, Wv, Wa, b2, Vp, c1);
    k_M   <<<dim3(4, NH), 256, 0, stream>>>(W1, Vp, b1, bv, ba, c1, Mb, c3);
    k_gemm<<<dim3(BB/GBM, JJ/GBN), 256, 0, stream>>>(Xb, Mb, c3, out);
}

// Round 9
// 39.523 us; speedup vs baseline: 1.5196x; 1.5196x over previous
//
#include <hip/hip_runtime.h>
#include <hip/hip_bf16.h>

#define DD   512
#define NH   32
#define AA   18
#define JJ   (NH*AA)          // 576
#define BB   4096
#define JD   (JJ*DD)          // 294912

typedef short bf16x8 __attribute__((ext_vector_type(8)));
typedef float f32x4  __attribute__((ext_vector_type(4)));

static __device__ inline unsigned short f2bf(float f) {
    unsigned int x = __float_as_uint(f);
    unsigned int r = (x + 0x7fffu + ((x >> 16) & 1u)) >> 16;   // RNE
    return (unsigned short)r;
}
static __device__ inline float bf2f(unsigned short bits) {
    return __uint_as_float((unsigned int)bits << 16);
}

// ---------------------------------------------------------------------------
// K1 (R7-validated core): per (dc,n):
//  a) stage U[a,e] = Wv + Wa - mean(Wa) as bf16, XOR-swizzled LDS;
//     dc==0 blocks also fold c1[j] = sum_e U[j,e]*b2[n,e]
//  b) V[n*18+a, d0..d0+32) = sum_e U[a,e] * W2[n,e,d]  via 16x16x32 MFMA.
//     grid (16 dc x 32 n) = 512 blocks, 256 thr (4 waves), LDS 32.3 KB.
// ---------------------------------------------------------------------------
__global__ __launch_bounds__(256) void k_V(
    const float* __restrict__ W2, const float* __restrict__ Wv,
    const float* __restrict__ Wa, const float* __restrict__ b2,
    unsigned short* __restrict__ Vb, float* __restrict__ c1)
{
    const int t  = threadIdx.x;
    const int dc = blockIdx.x;          // 0..15
    const int n  = blockIdx.y;          // 0..31

    __shared__ __align__(16) unsigned short usb[32 * DD];   // 32 KB bf16
    __shared__ float redc[AA * 4];

    // --- a) stage U (thread owns e = 2t, 2t+1), swizzled bf16 pair-writes
    {
        const int e = 2*t;
        float u0[AA], u1[AA];
        float msum0 = 0.f, msum1 = 0.f;
        #pragma unroll
        for (int a = 0; a < AA; ++a) {
            const float2 w = *(const float2*)(Wa + (size_t)(n*AA + a)*DD + e);
            u0[a] = w.x; u1[a] = w.y; msum0 += w.x; msum1 += w.y;
        }
        msum0 *= (1.0f/18.0f); msum1 *= (1.0f/18.0f);
        const float2 wv  = *(const float2*)(Wv + (size_t)n*DD + e);
        const float2 b2v = *(const float2*)(b2 + (size_t)n*DD + e);
        float p[AA];
        #pragma unroll
        for (int a = 0; a < AA; ++a) {
            u0[a] = wv.x + u0[a] - msum0;
            u1[a] = wv.y + u1[a] - msum1;
            const unsigned int pk = ((unsigned int)f2bf(u1[a]) << 16) | f2bf(u0[a]);
            const int slot = (t >> 2) ^ (a & 7);          // 16B-slot swizzle
            *(unsigned int*)(usb + a*DD + slot*8 + (t & 3)*2) = pk;
            p[a] = u0[a]*b2v.x + u1[a]*b2v.y;
        }
        if (dc == 0) {   // c1 fold (R5-validated reduce)
            #pragma unroll
            for (int a = 0; a < AA; ++a)
                for (int o = 32; o; o >>= 1) p[a] += __shfl_xor(p[a], o, 64);
            if ((t & 63) == 0) {
                const int w = t >> 6;
                #pragma unroll
                for (int a = 0; a < AA; ++a) redc[a*4 + w] = p[a];
            }
            __syncthreads();
            if (t < AA)
                c1[n*AA + t] = redc[t*4] + redc[t*4+1] + redc[t*4+2] + redc[t*4+3];
        }
    }
    __syncthreads();

    // --- b) MFMA contraction
    const int lane = t & 63, w = t >> 6;
    const int wp = w & 1;                 // a-tile (0: a 0..15, 1: a 16..17+pad)
    const int wd = w >> 1;                // d-sub-tile
    const int ln = lane & 15, lg = lane >> 4;
    const int d0 = dc*32 + wd*16;
    const int arow = wp*16 + ln;
    const float* w2base = W2 + (size_t)n*DD*DD + d0 + ln;

    f32x4 acc = {};
    #pragma unroll 4
    for (int kt = 0; kt < 16; ++kt) {
        const float* gp = w2base + (size_t)(kt*32 + lg*8)*DD;
        float wvv[8];
        #pragma unroll
        for (int j = 0; j < 8; ++j) wvv[j] = gp[(size_t)j*DD];
        bf16x8 bfrag;
        #pragma unroll
        for (int j = 0; j < 8; ++j) bfrag[j] = (short)f2bf(wvv[j]);
        const int slot = (kt*4 + lg) ^ (arow & 7);
        const bf16x8 afrag = *(const bf16x8*)(usb + arow*DD + slot*8);
        acc = __builtin_amdgcn_mfma_f32_16x16x32_bf16(afrag, bfrag, acc, 0, 0, 0);
    }

    // D layout: col=lane&15 (d), row=(lane>>4)*4+reg (a)   [m89/m91]
    #pragma unroll
    for (int r = 0; r < 4; ++r) {
        const int a = wp*16 + lg*4 + r;
        if (a < AA)
            Vb[(size_t)(n*AA + a)*DD + d0 + ln] = f2bf(acc[r]);
    }
}

// ---------------------------------------------------------------------------
// K2 (R7-validated core): per (kc,n):
//  a) kc==0: c3[j] = c1[j] + sum_d V[j,d]*b1[n,d] + bv[n] + ba[j] - mean(ba)
//  b) M[n*18+a, k0..k0+32) = sum_d V[a,d] * W1[n*512+d, k] -> bf16 (MFMA)
// ---------------------------------------------------------------------------
__global__ __launch_bounds__(256) void k_M(
    const float* __restrict__ W1, const unsigned short* __restrict__ Vb,
    const float* __restrict__ b1, const float* __restrict__ bv,
    const float* __restrict__ ba, const float* __restrict__ c1,
    unsigned short* __restrict__ Mb, float* __restrict__ c3)
{
    const int t  = threadIdx.x;
    const int kc = blockIdx.x;          // 0..15
    const int n  = blockIdx.y;          // 0..31

    __shared__ __align__(16) unsigned short vsb[32 * DD];   // 32 KB bf16
    __shared__ float redc[AA * 4];

    // stage V -> LDS swizzled (b128 both sides)
    for (int idx = t; idx < AA*64; idx += 256) {
        const int row = idx >> 6, slot = idx & 63;
        const int4 v = *(const int4*)(Vb + (size_t)(n*AA + row)*DD + slot*8);
        *(int4*)(vsb + row*DD + ((slot ^ (row & 7))*8)) = v;
    }
    __syncthreads();

    // --- a) c3 on kc==0 blocks (reads Vb global, pairwise)
    if (kc == 0) {
        const int e = 2*t;
        const float2 b1v = *(const float2*)(b1 + (size_t)n*DD + e);
        float p[AA];
        #pragma unroll
        for (int a = 0; a < AA; ++a) {
            const unsigned int pk = *(const unsigned int*)(Vb + (size_t)(n*AA + a)*DD + e);
            p[a] = bf2f((unsigned short)(pk & 0xffffu))*b1v.x
                 + bf2f((unsigned short)(pk >> 16))*b1v.y;
        }
        #pragma unroll
        for (int a = 0; a < AA; ++a)
            for (int o = 32; o; o >>= 1) p[a] += __shfl_xor(p[a], o, 64);
        if ((t & 63) == 0) {
            const int w = t >> 6;
            #pragma unroll
            for (int a = 0; a < AA; ++a) redc[a*4 + w] = p[a];
        }
        __syncthreads();
        if (t < AA) {
            float bam = 0.f;
            #pragma unroll
            for (int a = 0; a < AA; ++a) bam += ba[n*AA + a];
            c3[n*AA + t] = c1[n*AA + t]
                         + redc[t*4] + redc[t*4+1] + redc[t*4+2] + redc[t*4+3]
                         + bv[n] + ba[n*AA + t] - bam * (1.0f/18.0f);
        }
    }

    // --- b) MFMA contraction over d
    const int lane = t & 63, w = t >> 6;
    const int wp = w & 1;
    const int wd = w >> 1;
    const int ln = lane & 15, lg = lane >> 4;
    const int k0 = kc*32 + wd*16;
    const int arow = wp*16 + ln;
    const float* w1base = W1 + (size_t)n*DD*DD + k0 + ln;

    f32x4 acc = {};
    #pragma unroll 4
    for (int kt = 0; kt < 16; ++kt) {
        const float* gp = w1base + (size_t)(kt*32 + lg*8)*DD;
        float wvv[8];
        #pragma unroll
        for (int j = 0; j < 8; ++j) wvv[j] = gp[(size_t)j*DD];
        bf16x8 bfrag;
        #pragma unroll
        for (int j = 0; j < 8; ++j) bfrag[j] = (short)f2bf(wvv[j]);
        const int slot = (kt*4 + lg) ^ (arow & 7);
        const bf16x8 afrag = *(const bf16x8*)(vsb + arow*DD + slot*8);
        acc = __builtin_amdgcn_mfma_f32_16x16x32_bf16(afrag, bfrag, acc, 0, 0, 0);
    }

    #pragma unroll
    for (int r = 0; r < 4; ++r) {
        const int a = wp*16 + lg*4 + r;
        if (a < AA)
            Mb[(size_t)(n*AA + a)*DD + k0 + ln] = f2bf(acc[r]);
    }
}

// ---------------------------------------------------------------------------
// K3: out[b,j] = sum_k x[b,k]*Mb[j,k] + c3[j]   (bf16 MFMA)
//     R5/R6-validated BM=64 BN=64 BK=64 geometry; X now staged DIRECTLY
//     from f32 x with cvt during LDS write (removes the convX pass).
// ---------------------------------------------------------------------------
#define GBM 64
#define GBN 64
#define GBK 64

__global__ __launch_bounds__(256) void k_gemm(
    const float* __restrict__ x,             // [4096][512] f32
    const unsigned short* __restrict__ Mb,   // [576][512]  bf16 bits
    const float* __restrict__ c3, float* __restrict__ out)
{
    __shared__ __align__(16) unsigned short xs[GBM * GBK];   // 8 KB
    __shared__ __align__(16) unsigned short ms[GBN * GBK];   // 8 KB

    const int t    = threadIdx.x;
    const int w    = t >> 6;
    const int lane = t & 63;
    const int ln   = lane & 15, lg = lane >> 4;
    const int wm   = w >> 1,   wn = w & 1;
    const int b0 = blockIdx.x * GBM;
    const int j0 = blockIdx.y * GBN;

    f32x4 acc[2][2] = {};

    for (int kc = 0; kc < DD; kc += GBK) {
        // stage X: 512 16B-dest slots; each thread cvt's 8 f32 -> 8 bf16
        #pragma unroll
        for (int it = 0; it < 2; ++it) {
            const int chunk = it*256 + t;
            const int row = chunk >> 3, slot = chunk & 7;
            const float* xp = x + (size_t)(b0 + row)*DD + kc + slot*8;
            const float4 a0 = *(const float4*)(xp);
            const float4 a1 = *(const float4*)(xp + 4);
            int4 vv;
            vv.x = (int)(((unsigned int)f2bf(a0.y) << 16) | f2bf(a0.x));
            vv.y = (int)(((unsigned int)f2bf(a0.w) << 16) | f2bf(a0.z));
            vv.z = (int)(((unsigned int)f2bf(a1.y) << 16) | f2bf(a1.x));
            vv.w = (int)(((unsigned int)f2bf(a1.w) << 16) | f2bf(a1.z));
            *(int4*)(xs + row*GBK + ((slot ^ (row & 7)) * 8)) = vv;
            // stage M: direct bf16 copy
            const int4 vm = *(const int4*)(Mb + (size_t)(j0 + row)*DD + kc + slot*8);
            *(int4*)(ms + row*GBK + ((slot ^ (row & 7)) * 8)) = vm;
        }
        __syncthreads();

        #pragma unroll
        for (int kk = 0; kk < 2; ++kk) {
            bf16x8 av[2], bv[2];
            #pragma unroll
            for (int mt = 0; mt < 2; ++mt) {
                const int row  = 32*wm + 16*mt + ln;
                const int slot = (4*kk + lg) ^ (row & 7);
                av[mt] = *(const bf16x8*)(xs + row*GBK + slot*8);
            }
            #pragma unroll
            for (int nt = 0; nt < 2; ++nt) {
                const int row  = 32*wn + 16*nt + ln;
                const int slot = (4*kk + lg) ^ (row & 7);
                bv[nt] = *(const bf16x8*)(ms + row*GBK + slot*8);
            }
            #pragma unroll
            for (int mt = 0; mt < 2; ++mt)
                #pragma unroll
                for (int nt = 0; nt < 2; ++nt)
                    acc[mt][nt] = __builtin_amdgcn_mfma_f32_16x16x32_bf16(
                        av[mt], bv[nt], acc[mt][nt], 0, 0, 0);
        }
        __syncthreads();
    }

    // C/D layout: col=lane&15, row=(lane>>4)*4+reg  [m89/m91]
    float c3v[2];
    #pragma unroll
    for (int nt = 0; nt < 2; ++nt) c3v[nt] = c3[j0 + 32*wn + 16*nt + ln];

    #pragma unroll
    for (int mt = 0; mt < 2; ++mt)
        #pragma unroll
        for (int nt = 0; nt < 2; ++nt) {
            const int j = j0 + 32*wn + 16*nt + ln;
            #pragma unroll
            for (int r = 0; r < 4; ++r) {
                const int b = b0 + 32*wm + 16*mt + 4*lg + r;
                out[(size_t)b*JJ + j] = acc[mt][nt][r] + c3v[nt];
            }
        }
}

// ---------------------------------------------------------------------------
extern "C" void kernel_launch(void* const* d_in, const int* in_sizes, int n_in,
                              void* d_out, int out_size, void* d_ws, size_t ws_size,
                              hipStream_t stream)
{
    const float* x  = (const float*)d_in[0];
    const float* W1 = (const float*)d_in[1];
    const float* b1 = (const float*)d_in[2];
    const float* W2 = (const float*)d_in[3];
    const float* b2 = (const float*)d_in[4];
    const float* Wv = (const float*)d_in[5];
    const float* bv = (const float*)d_in[6];
    const float* Wa = (const float*)d_in[7];
    const float* ba = (const float*)d_in[8];
    float* out = (float*)d_out;
    float* ws  = (float*)d_ws;

    // workspace: c1[JJ] f32 | c3[JJ] f32 | Vb[JD] u16 | Mb[JD] u16
    float* c1 = ws;
    float* c3 = c1 + JJ;
    unsigned short* Vb = (unsigned short*)(c3 + JJ);
    unsigned short* Mb = Vb + (size_t)JD;

    k_V   <<<dim3(16, NH), 256, 0, stream>>>(W2, Wv, Wa, b2, Vb, c1);
    k_M   <<<dim3(16, NH), 256, 0, stream>>>(W1, Vb, b1, bv, ba, c1, Mb, c3);
    k_gemm<<<dim3(BB/GBM, JJ/GBN), 256, 0, stream>>>(x, Mb, c3, out);
}